// Round 12
// baseline (398.798 us; speedup 1.0000x reference)
//
#include <hip/hip_runtime.h>
#include <hip/hip_bf16.h>
#include <math.h>

#define EMB 768
#define HEADS 12
#define DKH 64
#define DFF 3072
#define NB 16
#define SEQ 577
#define MTOK (NB*SEQ)      // 9232
#define BHN (NB*HEADS)     // 192
#define VLD 640            // vT row stride (bf16 elems)

typedef __attribute__((ext_vector_type(8))) short short8;
typedef __attribute__((ext_vector_type(4))) float f32x4;

__device__ __forceinline__ unsigned short f2bf(float f) {
  __hip_bfloat16 h = __float2bfloat16(f);
  return *reinterpret_cast<unsigned short*>(&h);
}

// fast GELU: x * sigmoid(2*0.79788456*(x + 0.044715 x^3)); |err| < ~1.5e-3
__device__ __forceinline__ float gelu_f(float x) {
  float u = x * (1.5957691216f + 0.0713548162726f * x * x);
  return x / (1.0f + __expf(-u));
}

__device__ __forceinline__ void gld_lds16(const unsigned short* g, unsigned short* l) {
  __builtin_amdgcn_global_load_lds(
      (const __attribute__((address_space(1))) unsigned int*)(g),
      (__attribute__((address_space(3))) unsigned int*)(l), 16, 0, 0);
}

template<int N> __device__ __forceinline__ void waitcnt_vm() {
  if constexpr (N == 0) asm volatile("s_waitcnt vmcnt(0)" ::: "memory");
  else if constexpr (N == 1) asm volatile("s_waitcnt vmcnt(1)" ::: "memory");
  else if constexpr (N == 2) asm volatile("s_waitcnt vmcnt(2)" ::: "memory");
  else if constexpr (N == 3) asm volatile("s_waitcnt vmcnt(3)" ::: "memory");
  else if constexpr (N == 4) asm volatile("s_waitcnt vmcnt(4)" ::: "memory");
  else if constexpr (N == 5) asm volatile("s_waitcnt vmcnt(5)" ::: "memory");
  else if constexpr (N == 6) asm volatile("s_waitcnt vmcnt(6)" ::: "memory");
  else if constexpr (N == 7) asm volatile("s_waitcnt vmcnt(7)" ::: "memory");
  else if constexpr (N == 8) asm volatile("s_waitcnt vmcnt(8)" ::: "memory");
}

// ---------------- LayerNorm: fp32 [row,768] -> bf16 [row,768] ----------------
__global__ __launch_bounds__(256) void ln_kernel(
    const float* __restrict__ x, const float* __restrict__ g,
    const float* __restrict__ b, unsigned short* __restrict__ out) {
  int row = blockIdx.x;
  int tid = threadIdx.x;
  const float* xr = x + (long)row * EMB;
  float v0 = xr[tid], v1 = xr[tid + 256], v2 = xr[tid + 512];
  float s = v0 + v1 + v2;
  float sq = v0*v0 + v1*v1 + v2*v2;
  for (int off = 32; off; off >>= 1) {
    s  += __shfl_down(s,  off, 64);
    sq += __shfl_down(sq, off, 64);
  }
  __shared__ float sh[8];
  int wid = tid >> 6, lane = tid & 63;
  if (lane == 0) { sh[wid] = s; sh[4 + wid] = sq; }
  __syncthreads();
  s  = sh[0] + sh[1] + sh[2] + sh[3];
  sq = sh[4] + sh[5] + sh[6] + sh[7];
  float mu = s * (1.0f / EMB);
  float var = sq * (1.0f / EMB) - mu * mu;
  float rs = rsqrtf(var + 1e-5f);
  unsigned short* orow = out + (long)row * EMB;
  orow[tid]       = f2bf((v0 - mu) * rs * g[tid]       + b[tid]);
  orow[tid + 256] = f2bf((v1 - mu) * rs * g[tid + 256] + b[tid + 256]);
  orow[tid + 512] = f2bf((v2 - mu) * rs * g[tid + 512] + b[tid + 512]);
}

// -------- all six weight transposes (fp32 [R,C] -> bf16 [C,R]) in one --------
__global__ __launch_bounds__(256) void transpose_all(
    const float* __restrict__ wq, const float* __restrict__ wk,
    const float* __restrict__ wv, const float* __restrict__ wo,
    const float* __restrict__ w1, const float* __restrict__ w2,
    unsigned short* __restrict__ WqkvT, unsigned short* __restrict__ WoT,
    unsigned short* __restrict__ W1T, unsigned short* __restrict__ W2T) {
  __shared__ float t[32][33];
  const int z = blockIdx.z;
  const int bx = blockIdx.x, by = blockIdx.y;
  const float* src; unsigned short* dst; int R, C, r0, c0;
  if (z < 4) {
    if (bx >= 24) return;
    R = 768; C = 768; r0 = by*32; c0 = bx*32;
    src = (z == 0) ? wq : (z == 1) ? wk : (z == 2) ? wv : wo;
    dst = (z == 0) ? WqkvT : (z == 1) ? WqkvT + 768*768 : (z == 2) ? WqkvT + 2*768*768 : WoT;
  } else if (z == 4) {
    R = 768; C = 3072; r0 = by*32; c0 = bx*32; src = w1; dst = W1T;
  } else {
    R = 3072; C = 768; r0 = bx*32; c0 = by*32; src = w2; dst = W2T;
  }
  int tx = threadIdx.x & 31, ty = threadIdx.x >> 5;
#pragma unroll
  for (int l = 0; l < 4; l++)
    t[ty + l*8][tx] = src[(long)(r0 + ty + l*8) * C + c0 + tx];
  __syncthreads();
#pragma unroll
  for (int l = 0; l < 4; l++)
    dst[(long)(c0 + ty + l*8) * R + r0 + tx] = f2bf(t[tx][ty + l*8]);
}

// ------------------- concat bq|bk|bv into one fp32[2304] ---------------------
__global__ void concat_bias(const float* __restrict__ a, const float* __restrict__ b,
                            const float* __restrict__ c, float* __restrict__ o) {
  int i = blockIdx.x * 256 + threadIdx.x;
  if (i < 768) o[i] = a[i];
  else if (i < 1536) o[i] = b[i - 768];
  else if (i < 2304) o[i] = c[i - 1536];
}

// --------- vT: qkv v-part [b,s,h,d] -> vT[bh][d][s] (row stride VLD) ---------
__global__ __launch_bounds__(256) void transpose_v(
    const unsigned short* __restrict__ qkv, unsigned short* __restrict__ vT) {
  __shared__ unsigned short t[32][33];
  int bhi = blockIdx.z;
  int b = bhi / HEADS, h = bhi % HEADS;
  int s0 = blockIdx.x * 32, d0 = blockIdx.y * 32;
  int tx = threadIdx.x & 31, ty = threadIdx.x >> 5;
  const unsigned short* base = qkv + ((long)b * SEQ) * (3*EMB) + 2*EMB + h*DKH;
#pragma unroll
  for (int l = 0; l < 4; l++) {
    int s = s0 + ty + l*8;
    t[ty + l*8][tx] = (s < SEQ) ? base[(long)s * (3*EMB) + d0 + tx] : (unsigned short)0;
  }
  __syncthreads();
  unsigned short* ob = vT + ((long)bhi * DKH) * VLD;
#pragma unroll
  for (int l = 0; l < 4; l++) {
    int d = d0 + ty + l*8;
    int s = s0 + tx;
    if (s < SEQ) ob[(long)d * VLD + s] = t[tx][ty + l*8];
  }
}

// ---- BK=64 GEMM: 128x128, 2-buf — ALL four big GEMMs ------------------------
// Warm-run measured (R9/R10/R11): halved barrier count wins even at multi-wave
// grids — warm L2/L3 residency removes the latency cost of 2 blocks/CU.
// Per iter: 8 staging loads | vmcnt(8) | barrier | 16 ds_read_b128 + 32 MFMA |
// lgkmcnt(0) | barrier.  Accumulation order identical to BK=32 ->
// bit-identical results.  LDS row = 64 elems; 16B k-group g at g ^ (row&7).
template<bool BIAS, bool RESID, bool GELU_, bool OF32>
__global__ __launch_bounds__(256) void gemm_k64(
    const unsigned short* __restrict__ A,    // [M][K]
    const unsigned short* __restrict__ Bt,   // [N][K]
    const float* __restrict__ bias,
    const float* __restrict__ resid,
    float* __restrict__ outf,
    unsigned short* __restrict__ outb,
    int M, int N, int K, int lda, int ldb, int ldc,
    int CX, int CY) {
  // A bufs: [2][8192] then B bufs: [2][8192] (elems)
  __shared__ __align__(16) unsigned short lds[4 * 8192];
  constexpr int BOFF = 2 * 8192;

  const int bid = blockIdx.x;
  const int xcd = bid & 7;
  const int sidx = bid >> 3;
  const int colt = sidx % CX;
  const int band = (sidx / CX) * 8 + xcd;
  if (band >= CY) return;
  const int m0 = band * 128, n0 = colt * 128;

  const int tid = threadIdx.x;
  const int wave = tid >> 6, lane = tid & 63;
  const int wm = (wave >> 1) * 64, wn = (wave & 1) * 64;
  const int lm = lane & 15, q = lane >> 4;

  const int srow = tid >> 3;                          // 0..31
  const int gcol = ((tid & 7) ^ (srow & 7)) * 8;      // swizzled 16B k-group

  int gma[4], gnb[4];
#pragma unroll
  for (int r = 0; r < 4; r++) {
    gma[r] = m0 + r*32 + srow;
    if (gma[r] > M - 1) gma[r] = M - 1;
    gnb[r] = n0 + r*32 + srow;
  }

  auto stage = [&](int kt, int buf) {
    const long k0 = (long)(kt << 6) + gcol;
#pragma unroll
    for (int r = 0; r < 4; r++)
      gld_lds16(A + (long)gma[r] * lda + k0, &lds[buf*8192 + r*2048 + 8*tid]);
#pragma unroll
    for (int r = 0; r < 4; r++)
      gld_lds16(Bt + (long)gnb[r] * ldb + k0, &lds[BOFF + buf*8192 + r*2048 + 8*tid]);
  };

  f32x4 acc[4][4];
#pragma unroll
  for (int i = 0; i < 4; i++)
#pragma unroll
    for (int j = 0; j < 4; j++) acc[i][j] = (f32x4){0,0,0,0};

  const int iters = K >> 6;
  stage(0, 0);
  for (int t = 0; t < iters; t++) {
    const int cb = t & 1;
    if (t + 1 < iters) {
      stage(t + 1, cb ^ 1);
      waitcnt_vm<8>();                    // stage(t) landed; 8 newest in flight
    } else {
      waitcnt_vm<0>();
    }
    asm volatile("s_barrier" ::: "memory");

#pragma unroll
    for (int kk = 0; kk < 2; kk++) {
      short8 af[4], bf[4];
#pragma unroll
      for (int i = 0; i < 4; i++) {
        int a = wm + i*16 + lm;
        af[i] = *(const short8*)&lds[cb*8192 + a*64 + (((kk*4 + q) ^ (a & 7)) * 8)];
      }
#pragma unroll
      for (int j = 0; j < 4; j++) {
        int b = wn + j*16 + lm;
        bf[j] = *(const short8*)&lds[BOFF + cb*8192 + b*64 + (((kk*4 + q) ^ (b & 7)) * 8)];
      }
#pragma unroll
      for (int i = 0; i < 4; i++)
#pragma unroll
        for (int j = 0; j < 4; j++)
          acc[i][j] = __builtin_amdgcn_mfma_f32_16x16x32_bf16(af[i], bf[j], acc[i][j], 0, 0, 0);
    }

    asm volatile("s_waitcnt lgkmcnt(0)" ::: "memory");
    asm volatile("s_barrier" ::: "memory");
  }

  if constexpr (!OF32) {
    // ---- coalesced bf16 epilogue (wave-private 64x64 region) [R6] ----
    unsigned short* ep = &lds[wave * 4096];
#pragma unroll
    for (int i = 0; i < 4; i++) {
#pragma unroll
      for (int j = 0; j < 4; j++) {
        int col = n0 + wn + j*16 + lm;
        float bv = BIAS ? bias[col] : 0.0f;
#pragma unroll
        for (int r = 0; r < 4; r++) {
          float v = acc[i][j][r] + bv;
          if (GELU_) v = gelu_f(v);
          int lrow = i*16 + q*4 + r;                       // 0..63
          int sg = (j*2 + (lm >> 3)) ^ (lrow & 7);         // swizzled 8-col group
          ep[lrow*64 + sg*8 + (lm & 7)] = f2bf(v);
        }
      }
    }
#pragma unroll
    for (int rr = 0; rr < 8; rr++) {
      int lrow = rr*8 + (lane >> 3);                       // 0..63
      int g = lane & 7;                                    // logical group
      short8 vv = *(const short8*)&ep[lrow*64 + ((g ^ (lrow & 7))*8)];
      int grow = m0 + wm + lrow;
      if (grow < M)
        *(short8*)&outb[(long)grow * ldc + n0 + wn + g*8] = vv;
    }
  } else {
    // ---- coalesced fp32 epilogue, chunked 16 rows (wave tile 64x64) [R8] ----
    // wave region: 16 rows x 68 words (2-way max aliasing), 4416B
    float* epf = (float*)&lds[0] + wave * 1104;
    const int rrow = lane >> 2;                          // 0..15
#pragma unroll
    for (int i = 0; i < 4; i++) {                        // chunk == i
#pragma unroll
      for (int j = 0; j < 4; j++) {
        int col = n0 + wn + j*16 + lm;
        float bv = BIAS ? bias[col] : 0.0f;
        int slot = j*4 + (lm >> 2);                      // 0..15
#pragma unroll
        for (int r = 0; r < 4; r++) {
          int lr = q*4 + r;                              // 0..15
          float v = acc[i][j][r] + bv;
          if (GELU_) v = gelu_f(v);
          epf[lr*68 + ((slot ^ (lr & 7)) << 2) + (lm & 3)] = v;
        }
      }
      int grow = m0 + wm + i*16 + rrow;
#pragma unroll
      for (int k = 0; k < 4; k++) {
        int s = (lane & 3) + k*4;                        // 0..15
        f32x4 vv = *(f32x4*)&epf[rrow*68 + ((s ^ (rrow & 7)) << 2)];
        if (grow < M) {
          long o = (long)grow * ldc + n0 + wn + s*4;
          if (RESID) {
            f32x4 rv = *(const f32x4*)&resid[o];
            vv = vv + rv;
          }
          *(f32x4*)&outf[o] = vv;
        }
      }
    }
  }
}

// ------- flash attention v2: fixed-shift softmax, Q128, swizzled LDS ---------
// softmax(s) == exp(s-8)/sum(exp(s-8)) exactly (scores bounded ~|15|).
// K/V double-buffered with counted vmcnt (gemm-k64 pattern): buf0 = Ks/Vs,
// buf1 = Qs (dead after qf is read into registers; 16KB = K 8KB + V 8KB).
// Per iter: issue stage(kt+1) into other buf | vmcnt(4) retires stage(kt) |
// barrier | compute | barrier (seals buf reads 1 iter before overwrite).
#define QT 128
__global__ __launch_bounds__(256) void flash_attn2(
    const unsigned short* __restrict__ qkv,   // [MTOK][2304], q|k|v
    const unsigned short* __restrict__ vT,    // [bh][64][VLD]
    unsigned short* __restrict__ ctx) {       // [MTOK][768]
  __shared__ unsigned short Qs[QT * 64];      // Q stage, then KV buf1
  __shared__ unsigned short Ks[64 * 64];      // KV buf0 K
  __shared__ unsigned short Vs[64 * 64];      // KV buf0 V
  __shared__ unsigned short Ps[QT * 64];

  const int q0 = blockIdx.x * QT;
  const int bh = blockIdx.y;
  const int b = bh / HEADS, h = bh % HEADS;
  const int tid = threadIdx.x;
  const int wave = tid >> 6, lane = tid & 63;
  const int lm = lane & 15, q = lane >> 4;
  const int xlm = (lm >> 1) & 3;

  const int sr = tid >> 3;
  const int gcol = ((tid & 7) ^ ((sr >> 1) & 3)) * 8;

  // ---- stage Q (128 rows, 4 chunks) ----
#pragma unroll
  for (int it = 0; it < 4; it++) {
    int r = sr + it*32;
    int s = q0 + r; if (s > SEQ - 1) s = SEQ - 1;
    gld_lds16(qkv + ((long)(b*SEQ + s))*(3*EMB) + h*DKH + gcol, &Qs[8*tid + it*2048]);
  }
  waitcnt_vm<0>();
  __syncthreads();

  short8 qf[2][2];
#pragma unroll
  for (int rt = 0; rt < 2; rt++)
#pragma unroll
    for (int kk = 0; kk < 2; kk++)
      qf[rt][kk] = *(const short8*)&Qs[(wave*32 + rt*16 + lm)*64 + ((kk*4 + q) ^ xlm)*8];

  __syncthreads();   // all qf reads complete before Qs is reused as KV buf1

  auto stageKV = [&](int kt, int buf) {
    unsigned short* kb = buf ? &Qs[0]    : Ks;
    unsigned short* vb = buf ? &Qs[4096] : Vs;
#pragma unroll
    for (int it = 0; it < 2; it++) {
      int r = sr + it*32;
      int s = kt*64 + r; if (s > SEQ - 1) s = SEQ - 1;
      gld_lds16(qkv + ((long)(b*SEQ + s))*(3*EMB) + EMB + h*DKH + gcol, &kb[8*tid + it*2048]);
      gld_lds16(vT + ((long)bh*DKH + r)*VLD + (long)kt*64 + gcol, &vb[8*tid + it*2048]);
    }
  };

  f32x4 oacc[2][4];
  float lsum[2][4];
#pragma unroll
  for (int rt = 0; rt < 2; rt++)
#pragma unroll
    for (int j = 0; j < 4; j++) oacc[rt][j] = (f32x4){0,0,0,0};
#pragma unroll
  for (int rt = 0; rt < 2; rt++)
#pragma unroll
    for (int r = 0; r < 4; r++) lsum[rt][r] = 0.f;

  stageKV(0, 0);

  for (int kt = 0; kt < 10; kt++) {
    if (kt < 9) {
      stageKV(kt + 1, (kt + 1) & 1);
      waitcnt_vm<4>();            // stage(kt) landed; kt+1's 4 loads in flight
    } else {
      waitcnt_vm<0>();
    }
    __syncthreads();

    const unsigned short* kb = (kt & 1) ? &Qs[0]    : Ks;
    const unsigned short* vb = (kt & 1) ? &Qs[4096] : Vs;

    // S = Q @ K^T (32 q-rows x 64 keys per wave)
    f32x4 sacc[2][4];
#pragma unroll
    for (int t = 0; t < 4; t++) {
      short8 kf0 = *(const short8*)&kb[(t*16 + lm)*64 + ((0 + q) ^ xlm)*8];
      short8 kf1 = *(const short8*)&kb[(t*16 + lm)*64 + ((4 + q) ^ xlm)*8];
      bool dead = (kt*64 + t*16 + lm) >= SEQ;
#pragma unroll
      for (int rt = 0; rt < 2; rt++) {
        f32x4 s0 = __builtin_amdgcn_mfma_f32_16x16x32_bf16(qf[rt][0], kf0, (f32x4){0,0,0,0}, 0, 0, 0);
        s0 = __builtin_amdgcn_mfma_f32_16x16x32_bf16(qf[rt][1], kf1, s0, 0, 0, 0);
        sacc[rt][t] = dead ? (f32x4){-1e30f,-1e30f,-1e30f,-1e30f} : s0;
      }
    }

    // exp(s-8), accumulate l, store P (swizzled, wave-private rows)
#pragma unroll
    for (int rt = 0; rt < 2; rt++)
#pragma unroll
      for (int t = 0; t < 4; t++)
#pragma unroll
        for (int r = 0; r < 4; r++) {
          float p = __expf(sacc[rt][t][r] - 8.0f);
          lsum[rt][r] += p;
          int row = wave*32 + rt*16 + q*4 + r;
          int g = (t*2 + (lm >> 3)) ^ ((q*2 + (r >> 1)) & 3);
          Ps[row*64 + g*8 + (lm & 7)] = f2bf(p);
        }

    // O += P @ V
#pragma unroll
    for (int kk = 0; kk < 2; kk++) {
      short8 vf[4];
#pragma unroll
      for (int j = 0; j < 4; j++)
        vf[j] = *(const short8*)&vb[(j*16 + lm)*64 + ((kk*4 + q) ^ xlm)*8];
#pragma unroll
      for (int rt = 0; rt < 2; rt++) {
        short8 pf = *(const short8*)&Ps[(wave*32 + rt*16 + lm)*64 + ((kk*4 + q) ^ xlm)*8];
#pragma unroll
        for (int j = 0; j < 4; j++)
          oacc[rt][j] = __builtin_amdgcn_mfma_f32_16x16x32_bf16(pf, vf[j], oacc[rt][j], 0, 0, 0);
      }
    }

    __syncthreads();   // seal this iter's kb/vb reads before buf reuse
  }

  // final l reduction across the 16 lm lanes (q bits untouched by xor<16)
#pragma unroll
  for (int rt = 0; rt < 2; rt++)
#pragma unroll
    for (int r = 0; r < 4; r++) {
      float l = lsum[rt][r];
      l += __shfl_xor(l, 1, 64);
      l += __shfl_xor(l, 2, 64);
      l += __shfl_xor(l, 4, 64);
      l += __shfl_xor(l, 8, 64);
      lsum[rt][r] = 1.0f / l;
    }

#pragma unroll
  for (int rt = 0; rt < 2; rt++)
#pragma unroll
    for (int j = 0; j < 4; j++)
#pragma unroll
      for (int r = 0; r < 4; r++) {
        int row = q0 + wave*32 + rt*16 + q*4 + r;
        if (row < SEQ)
          ctx[((long)(b*SEQ + row))*EMB + h*DKH + j*16 + lm] =
              f2bf(oacc[rt][j][r] * lsum[rt][r]);
      }
}

extern "C" void kernel_launch(void* const* d_in, const int* in_sizes, int n_in,
                              void* d_out, int out_size, void* d_ws, size_t ws_size,
                              hipStream_t stream) {
  const float* x     = (const float*)d_in[0];
  const float* wq    = (const float*)d_in[1];
  const float* bq    = (const float*)d_in[2];
  const float* wk    = (const float*)d_in[3];
  const float* bk    = (const float*)d_in[4];
  const float* wv    = (const float*)d_in[5];
  const float* bv    = (const float*)d_in[6];
  const float* wo    = (const float*)d_in[7];
  const float* bo    = (const float*)d_in[8];
  const float* w1    = (const float*)d_in[9];
  const float* bf1   = (const float*)d_in[10];
  const float* w2    = (const float*)d_in[11];
  const float* bf2   = (const float*)d_in[12];
  const float* ln1g  = (const float*)d_in[13];
  const float* ln1b  = (const float*)d_in[14];
  const float* ln2g  = (const float*)d_in[15];
  const float* ln2b  = (const float*)d_in[16];
  float* out = (float*)d_out;

  char* w = (char*)d_ws;
  size_t off = 0;
  auto alloc = [&](size_t bytes) -> void* {
    void* p = w + off;
    off = (off + bytes + 255) & ~(size_t)255;
    return p;
  };
  unsigned short* WqkvT = (unsigned short*)alloc((size_t)3 * 768 * 768 * 2);
  unsigned short* WoT   = (unsigned short*)alloc((size_t)768 * 768 * 2);
  unsigned short* W1T   = (unsigned short*)alloc((size_t)3072 * 768 * 2);
  unsigned short* W2T   = (unsigned short*)alloc((size_t)768 * 3072 * 2);
  float*          bqkv  = (float*)alloc(2304 * 4);
  unsigned short* hbuf  = (unsigned short*)alloc((size_t)MTOK * EMB * 2);
  unsigned short* qkv   = (unsigned short*)alloc((size_t)MTOK * 3 * EMB * 2);
  unsigned short* vT    = (unsigned short*)alloc((size_t)BHN * DKH * VLD * 2);
  float*          x1    = (float*)alloc((size_t)MTOK * EMB * 4);
  unsigned short* g     = (unsigned short*)alloc((size_t)MTOK * DFF * 2);
  (void)ws_size; (void)in_sizes; (void)n_in; (void)out_size;

  dim3 blk(256);
  const int B128 = ((73 + 7) / 8) * 8;    // 80 padded bands of 128 rows

  transpose_all<<<dim3(96, 24, 6), blk, 0, stream>>>(
      wq, wk, wv, wo, w1, w2, WqkvT, WoT, W1T, W2T);
  concat_bias<<<dim3(9), blk, 0, stream>>>(bq, bk, bv, bqkv);

  ln_kernel<<<dim3(MTOK), blk, 0, stream>>>(x, ln1g, ln1b, hbuf);

  // QKV: [9232,768] @ [768,2304], 128x128 BK=64 (12 iters), CX=18
  gemm_k64<true, false, false, false><<<dim3(18 * B128), blk, 0, stream>>>(
      hbuf, WqkvT, bqkv, nullptr, nullptr, qkv,
      MTOK, 3*EMB, EMB, EMB, EMB, 3*EMB, 18, 73);

  transpose_v<<<dim3(19, 2, BHN), blk, 0, stream>>>(qkv, vT);

  // fused attention v2 (K/V dbuf, counted vmcnt) -> ctx (hbuf)
  flash_attn2<<<dim3(5, BHN), blk, 0, stream>>>(qkv, vT, hbuf);

  // O-proj + residual -> x1 (fp32); 128x128 BK=64 (12 iters), CX=6
  gemm_k64<true, true, false, true><<<dim3(6 * B128), blk, 0, stream>>>(
      hbuf, WoT, bo, x, x1, nullptr,
      MTOK, EMB, EMB, EMB, EMB, EMB, 6, 73);

  ln_kernel<<<dim3(MTOK), blk, 0, stream>>>(x1, ln2g, ln2b, hbuf);

  // FFN1 + bias + fast GELU -> g (bf16); 128x128 BK=64 (12 iters), CX=24
  gemm_k64<true, false, true, false><<<dim3(24 * B128), blk, 0, stream>>>(
      hbuf, W1T, bf1, nullptr, nullptr, g,
      MTOK, DFF, EMB, EMB, EMB, DFF, 24, 73);

  // FFN2 + bias + residual -> out (fp32); 128x128 BK=64 (48 iters), CX=6
  gemm_k64<true, true, false, true><<<dim3(6 * B128), blk, 0, stream>>>(
      g, W2T, bf2, x1, out, nullptr,
      MTOK, EMB, DFF, DFF, DFF, EMB, 6, 73);
}

// Round 13
// 384.130 us; speedup vs baseline: 1.0382x; 1.0382x over previous
//
#include <hip/hip_runtime.h>
#include <hip/hip_bf16.h>
#include <math.h>

#define EMB 768
#define HEADS 12
#define DKH 64
#define DFF 3072
#define NB 16
#define SEQ 577
#define MTOK (NB*SEQ)      // 9232
#define BHN (NB*HEADS)     // 192
#define VLD 640            // vT row stride (bf16 elems)

typedef __attribute__((ext_vector_type(8))) short short8;
typedef __attribute__((ext_vector_type(4))) float f32x4;

__device__ __forceinline__ unsigned short f2bf(float f) {
  __hip_bfloat16 h = __float2bfloat16(f);
  return *reinterpret_cast<unsigned short*>(&h);
}

// fast GELU: x * sigmoid(2*0.79788456*(x + 0.044715 x^3)); |err| < ~1.5e-3
__device__ __forceinline__ float gelu_f(float x) {
  float u = x * (1.5957691216f + 0.0713548162726f * x * x);
  return x / (1.0f + __expf(-u));
}

__device__ __forceinline__ void gld_lds16(const unsigned short* g, unsigned short* l) {
  __builtin_amdgcn_global_load_lds(
      (const __attribute__((address_space(1))) unsigned int*)(g),
      (__attribute__((address_space(3))) unsigned int*)(l), 16, 0, 0);
}

template<int N> __device__ __forceinline__ void waitcnt_vm() {
  if constexpr (N == 0) asm volatile("s_waitcnt vmcnt(0)" ::: "memory");
  else if constexpr (N == 1) asm volatile("s_waitcnt vmcnt(1)" ::: "memory");
  else if constexpr (N == 2) asm volatile("s_waitcnt vmcnt(2)" ::: "memory");
  else if constexpr (N == 3) asm volatile("s_waitcnt vmcnt(3)" ::: "memory");
  else if constexpr (N == 4) asm volatile("s_waitcnt vmcnt(4)" ::: "memory");
  else if constexpr (N == 5) asm volatile("s_waitcnt vmcnt(5)" ::: "memory");
  else if constexpr (N == 6) asm volatile("s_waitcnt vmcnt(6)" ::: "memory");
  else if constexpr (N == 7) asm volatile("s_waitcnt vmcnt(7)" ::: "memory");
  else if constexpr (N == 8) asm volatile("s_waitcnt vmcnt(8)" ::: "memory");
}

// ---------------- LayerNorm: fp32 [row,768] -> bf16 [row,768] ----------------
__global__ __launch_bounds__(256) void ln_kernel(
    const float* __restrict__ x, const float* __restrict__ g,
    const float* __restrict__ b, unsigned short* __restrict__ out) {
  int row = blockIdx.x;
  int tid = threadIdx.x;
  const float* xr = x + (long)row * EMB;
  float v0 = xr[tid], v1 = xr[tid + 256], v2 = xr[tid + 512];
  float s = v0 + v1 + v2;
  float sq = v0*v0 + v1*v1 + v2*v2;
  for (int off = 32; off; off >>= 1) {
    s  += __shfl_down(s,  off, 64);
    sq += __shfl_down(sq, off, 64);
  }
  __shared__ float sh[8];
  int wid = tid >> 6, lane = tid & 63;
  if (lane == 0) { sh[wid] = s; sh[4 + wid] = sq; }
  __syncthreads();
  s  = sh[0] + sh[1] + sh[2] + sh[3];
  sq = sh[4] + sh[5] + sh[6] + sh[7];
  float mu = s * (1.0f / EMB);
  float var = sq * (1.0f / EMB) - mu * mu;
  float rs = rsqrtf(var + 1e-5f);
  unsigned short* orow = out + (long)row * EMB;
  orow[tid]       = f2bf((v0 - mu) * rs * g[tid]       + b[tid]);
  orow[tid + 256] = f2bf((v1 - mu) * rs * g[tid + 256] + b[tid + 256]);
  orow[tid + 512] = f2bf((v2 - mu) * rs * g[tid + 512] + b[tid + 512]);
}

// -------- all six weight transposes (fp32 [R,C] -> bf16 [C,R]) in one --------
__global__ __launch_bounds__(256) void transpose_all(
    const float* __restrict__ wq, const float* __restrict__ wk,
    const float* __restrict__ wv, const float* __restrict__ wo,
    const float* __restrict__ w1, const float* __restrict__ w2,
    unsigned short* __restrict__ WqkvT, unsigned short* __restrict__ WoT,
    unsigned short* __restrict__ W1T, unsigned short* __restrict__ W2T) {
  __shared__ float t[32][33];
  const int z = blockIdx.z;
  const int bx = blockIdx.x, by = blockIdx.y;
  const float* src; unsigned short* dst; int R, C, r0, c0;
  if (z < 4) {
    if (bx >= 24) return;
    R = 768; C = 768; r0 = by*32; c0 = bx*32;
    src = (z == 0) ? wq : (z == 1) ? wk : (z == 2) ? wv : wo;
    dst = (z == 0) ? WqkvT : (z == 1) ? WqkvT + 768*768 : (z == 2) ? WqkvT + 2*768*768 : WoT;
  } else if (z == 4) {
    R = 768; C = 3072; r0 = by*32; c0 = bx*32; src = w1; dst = W1T;
  } else {
    R = 3072; C = 768; r0 = bx*32; c0 = by*32; src = w2; dst = W2T;
  }
  int tx = threadIdx.x & 31, ty = threadIdx.x >> 5;
#pragma unroll
  for (int l = 0; l < 4; l++)
    t[ty + l*8][tx] = src[(long)(r0 + ty + l*8) * C + c0 + tx];
  __syncthreads();
#pragma unroll
  for (int l = 0; l < 4; l++)
    dst[(long)(c0 + ty + l*8) * R + r0 + tx] = f2bf(t[tx][ty + l*8]);
}

// ------------------- concat bq|bk|bv into one fp32[2304] ---------------------
__global__ void concat_bias(const float* __restrict__ a, const float* __restrict__ b,
                            const float* __restrict__ c, float* __restrict__ o) {
  int i = blockIdx.x * 256 + threadIdx.x;
  if (i < 768) o[i] = a[i];
  else if (i < 1536) o[i] = b[i - 768];
  else if (i < 2304) o[i] = c[i - 1536];
}

// --------- vT: qkv v-part [b,s,h,d] -> vT[bh][d][s] (row stride VLD) ---------
__global__ __launch_bounds__(256) void transpose_v(
    const unsigned short* __restrict__ qkv, unsigned short* __restrict__ vT) {
  __shared__ unsigned short t[32][33];
  int bhi = blockIdx.z;
  int b = bhi / HEADS, h = bhi % HEADS;
  int s0 = blockIdx.x * 32, d0 = blockIdx.y * 32;
  int tx = threadIdx.x & 31, ty = threadIdx.x >> 5;
  const unsigned short* base = qkv + ((long)b * SEQ) * (3*EMB) + 2*EMB + h*DKH;
#pragma unroll
  for (int l = 0; l < 4; l++) {
    int s = s0 + ty + l*8;
    t[ty + l*8][tx] = (s < SEQ) ? base[(long)s * (3*EMB) + d0 + tx] : (unsigned short)0;
  }
  __syncthreads();
  unsigned short* ob = vT + ((long)bhi * DKH) * VLD;
#pragma unroll
  for (int l = 0; l < 4; l++) {
    int d = d0 + ty + l*8;
    int s = s0 + tx;
    if (s < SEQ) ob[(long)d * VLD + s] = t[tx][ty + l*8];
  }
}

// ---- BK=64 GEMM: 128x128, 2-buf — ALL four big GEMMs ------------------------
// Warm-run measured (R9/R10/R11): halved barrier count wins even at multi-wave
// grids — warm L2/L3 residency removes the latency cost of 2 blocks/CU.
// Per iter: 8 staging loads | vmcnt(8) | barrier | 16 ds_read_b128 + 32 MFMA |
// lgkmcnt(0) | barrier.  Accumulation order identical to BK=32 ->
// bit-identical results.  LDS row = 64 elems; 16B k-group g at g ^ (row&7).
template<bool BIAS, bool RESID, bool GELU_, bool OF32>
__global__ __launch_bounds__(256) void gemm_k64(
    const unsigned short* __restrict__ A,    // [M][K]
    const unsigned short* __restrict__ Bt,   // [N][K]
    const float* __restrict__ bias,
    const float* __restrict__ resid,
    float* __restrict__ outf,
    unsigned short* __restrict__ outb,
    int M, int N, int K, int lda, int ldb, int ldc,
    int CX, int CY) {
  // A bufs: [2][8192] then B bufs: [2][8192] (elems)
  __shared__ __align__(16) unsigned short lds[4 * 8192];
  constexpr int BOFF = 2 * 8192;

  const int bid = blockIdx.x;
  const int xcd = bid & 7;
  const int sidx = bid >> 3;
  const int colt = sidx % CX;
  const int band = (sidx / CX) * 8 + xcd;
  if (band >= CY) return;
  const int m0 = band * 128, n0 = colt * 128;

  const int tid = threadIdx.x;
  const int wave = tid >> 6, lane = tid & 63;
  const int wm = (wave >> 1) * 64, wn = (wave & 1) * 64;
  const int lm = lane & 15, q = lane >> 4;

  const int srow = tid >> 3;                          // 0..31
  const int gcol = ((tid & 7) ^ (srow & 7)) * 8;      // swizzled 16B k-group

  int gma[4], gnb[4];
#pragma unroll
  for (int r = 0; r < 4; r++) {
    gma[r] = m0 + r*32 + srow;
    if (gma[r] > M - 1) gma[r] = M - 1;
    gnb[r] = n0 + r*32 + srow;
  }

  auto stage = [&](int kt, int buf) {
    const long k0 = (long)(kt << 6) + gcol;
#pragma unroll
    for (int r = 0; r < 4; r++)
      gld_lds16(A + (long)gma[r] * lda + k0, &lds[buf*8192 + r*2048 + 8*tid]);
#pragma unroll
    for (int r = 0; r < 4; r++)
      gld_lds16(Bt + (long)gnb[r] * ldb + k0, &lds[BOFF + buf*8192 + r*2048 + 8*tid]);
  };

  f32x4 acc[4][4];
#pragma unroll
  for (int i = 0; i < 4; i++)
#pragma unroll
    for (int j = 0; j < 4; j++) acc[i][j] = (f32x4){0,0,0,0};

  const int iters = K >> 6;
  stage(0, 0);
  for (int t = 0; t < iters; t++) {
    const int cb = t & 1;
    if (t + 1 < iters) {
      stage(t + 1, cb ^ 1);
      waitcnt_vm<8>();                    // stage(t) landed; 8 newest in flight
    } else {
      waitcnt_vm<0>();
    }
    asm volatile("s_barrier" ::: "memory");

#pragma unroll
    for (int kk = 0; kk < 2; kk++) {
      short8 af[4], bf[4];
#pragma unroll
      for (int i = 0; i < 4; i++) {
        int a = wm + i*16 + lm;
        af[i] = *(const short8*)&lds[cb*8192 + a*64 + (((kk*4 + q) ^ (a & 7)) * 8)];
      }
#pragma unroll
      for (int j = 0; j < 4; j++) {
        int b = wn + j*16 + lm;
        bf[j] = *(const short8*)&lds[BOFF + cb*8192 + b*64 + (((kk*4 + q) ^ (b & 7)) * 8)];
      }
#pragma unroll
      for (int i = 0; i < 4; i++)
#pragma unroll
        for (int j = 0; j < 4; j++)
          acc[i][j] = __builtin_amdgcn_mfma_f32_16x16x32_bf16(af[i], bf[j], acc[i][j], 0, 0, 0);
    }

    asm volatile("s_waitcnt lgkmcnt(0)" ::: "memory");
    asm volatile("s_barrier" ::: "memory");
  }

  if constexpr (!OF32) {
    // ---- coalesced bf16 epilogue (wave-private 64x64 region) [R6] ----
    unsigned short* ep = &lds[wave * 4096];
#pragma unroll
    for (int i = 0; i < 4; i++) {
#pragma unroll
      for (int j = 0; j < 4; j++) {
        int col = n0 + wn + j*16 + lm;
        float bv = BIAS ? bias[col] : 0.0f;
#pragma unroll
        for (int r = 0; r < 4; r++) {
          float v = acc[i][j][r] + bv;
          if (GELU_) v = gelu_f(v);
          int lrow = i*16 + q*4 + r;                       // 0..63
          int sg = (j*2 + (lm >> 3)) ^ (lrow & 7);         // swizzled 8-col group
          ep[lrow*64 + sg*8 + (lm & 7)] = f2bf(v);
        }
      }
    }
#pragma unroll
    for (int rr = 0; rr < 8; rr++) {
      int lrow = rr*8 + (lane >> 3);                       // 0..63
      int g = lane & 7;                                    // logical group
      short8 vv = *(const short8*)&ep[lrow*64 + ((g ^ (lrow & 7))*8)];
      int grow = m0 + wm + lrow;
      if (grow < M)
        *(short8*)&outb[(long)grow * ldc + n0 + wn + g*8] = vv;
    }
  } else {
    // ---- coalesced fp32 epilogue, chunked 16 rows (wave tile 64x64) [R8] ----
    // wave region: 16 rows x 68 words (2-way max aliasing), 4416B
    float* epf = (float*)&lds[0] + wave * 1104;
    const int rrow = lane >> 2;                          // 0..15
#pragma unroll
    for (int i = 0; i < 4; i++) {                        // chunk == i
#pragma unroll
      for (int j = 0; j < 4; j++) {
        int col = n0 + wn + j*16 + lm;
        float bv = BIAS ? bias[col] : 0.0f;
        int slot = j*4 + (lm >> 2);                      // 0..15
#pragma unroll
        for (int r = 0; r < 4; r++) {
          int lr = q*4 + r;                              // 0..15
          float v = acc[i][j][r] + bv;
          if (GELU_) v = gelu_f(v);
          epf[lr*68 + ((slot ^ (lr & 7)) << 2) + (lm & 3)] = v;
        }
      }
      int grow = m0 + wm + i*16 + rrow;
#pragma unroll
      for (int k = 0; k < 4; k++) {
        int s = (lane & 3) + k*4;                        // 0..15
        f32x4 vv = *(f32x4*)&epf[rrow*68 + ((s ^ (rrow & 7)) << 2)];
        if (grow < M) {
          long o = (long)grow * ldc + n0 + wn + s*4;
          if (RESID) {
            f32x4 rv = *(const f32x4*)&resid[o];
            vv = vv + rv;
          }
          *(f32x4*)&outf[o] = vv;
        }
      }
    }
  }
}

// ------- flash attention v2: fixed-shift softmax, Q128, swizzled LDS ---------
// softmax(s) == exp(s-8)/sum(exp(s-8)) exactly (scores bounded ~|15|).
// R11 single-buffer staging (5 blocks/CU TLP hides the vmcnt(0) drain;
// K/V dbuf measured -9us wall in R12 — reverted).  R13: s_setprio(1)
// around MFMA clusters (T5: pays when co-resident blocks are at different
// phases — 5 independent blocks/CU here, m191's attn case).
#define QT 128
__global__ __launch_bounds__(256) void flash_attn2(
    const unsigned short* __restrict__ qkv,   // [MTOK][2304], q|k|v
    const unsigned short* __restrict__ vT,    // [bh][64][VLD]
    unsigned short* __restrict__ ctx) {       // [MTOK][768]
  __shared__ unsigned short Qs[QT * 64];
  __shared__ unsigned short Ks[64 * 64];
  __shared__ unsigned short Vs[64 * 64];
  __shared__ unsigned short Ps[QT * 64];

  const int q0 = blockIdx.x * QT;
  const int bh = blockIdx.y;
  const int b = bh / HEADS, h = bh % HEADS;
  const int tid = threadIdx.x;
  const int wave = tid >> 6, lane = tid & 63;
  const int lm = lane & 15, q = lane >> 4;
  const int xlm = (lm >> 1) & 3;

  const int sr = tid >> 3;
  const int gcol = ((tid & 7) ^ ((sr >> 1) & 3)) * 8;

#pragma unroll
  for (int it = 0; it < 4; it++) {
    int r = sr + it*32;
    int s = q0 + r; if (s > SEQ - 1) s = SEQ - 1;
    gld_lds16(qkv + ((long)(b*SEQ + s))*(3*EMB) + h*DKH + gcol, &Qs[8*tid + it*2048]);
  }
  waitcnt_vm<0>();
  __syncthreads();

  short8 qf[2][2];
#pragma unroll
  for (int rt = 0; rt < 2; rt++)
#pragma unroll
    for (int kk = 0; kk < 2; kk++)
      qf[rt][kk] = *(const short8*)&Qs[(wave*32 + rt*16 + lm)*64 + ((kk*4 + q) ^ xlm)*8];

  f32x4 oacc[2][4];
  float lsum[2][4];
#pragma unroll
  for (int rt = 0; rt < 2; rt++)
#pragma unroll
    for (int j = 0; j < 4; j++) oacc[rt][j] = (f32x4){0,0,0,0};
#pragma unroll
  for (int rt = 0; rt < 2; rt++)
#pragma unroll
    for (int r = 0; r < 4; r++) lsum[rt][r] = 0.f;

  for (int kt = 0; kt < 10; kt++) {
    __syncthreads();   // prev iter's Ks/Vs reads complete
#pragma unroll
    for (int it = 0; it < 2; it++) {
      int r = sr + it*32;
      int s = kt*64 + r; if (s > SEQ - 1) s = SEQ - 1;
      gld_lds16(qkv + ((long)(b*SEQ + s))*(3*EMB) + EMB + h*DKH + gcol, &Ks[8*tid + it*2048]);
      gld_lds16(vT + ((long)bh*DKH + r)*VLD + (long)kt*64 + gcol, &Vs[8*tid + it*2048]);
    }
    waitcnt_vm<0>();
    __syncthreads();

    // S = Q @ K^T (32 q-rows x 64 keys per wave)
    f32x4 sacc[2][4];
    __builtin_amdgcn_s_setprio(1);
#pragma unroll
    for (int t = 0; t < 4; t++) {
      short8 kf0 = *(const short8*)&Ks[(t*16 + lm)*64 + ((0 + q) ^ xlm)*8];
      short8 kf1 = *(const short8*)&Ks[(t*16 + lm)*64 + ((4 + q) ^ xlm)*8];
      bool dead = (kt*64 + t*16 + lm) >= SEQ;
#pragma unroll
      for (int rt = 0; rt < 2; rt++) {
        f32x4 s0 = __builtin_amdgcn_mfma_f32_16x16x32_bf16(qf[rt][0], kf0, (f32x4){0,0,0,0}, 0, 0, 0);
        s0 = __builtin_amdgcn_mfma_f32_16x16x32_bf16(qf[rt][1], kf1, s0, 0, 0, 0);
        sacc[rt][t] = dead ? (f32x4){-1e30f,-1e30f,-1e30f,-1e30f} : s0;
      }
    }
    __builtin_amdgcn_s_setprio(0);

    // exp(s-8), accumulate l, store P (swizzled, wave-private rows)
#pragma unroll
    for (int rt = 0; rt < 2; rt++)
#pragma unroll
      for (int t = 0; t < 4; t++)
#pragma unroll
        for (int r = 0; r < 4; r++) {
          float p = __expf(sacc[rt][t][r] - 8.0f);
          lsum[rt][r] += p;
          int row = wave*32 + rt*16 + q*4 + r;
          int g = (t*2 + (lm >> 3)) ^ ((q*2 + (r >> 1)) & 3);
          Ps[row*64 + g*8 + (lm & 7)] = f2bf(p);
        }

    // O += P @ V
    __builtin_amdgcn_s_setprio(1);
#pragma unroll
    for (int kk = 0; kk < 2; kk++) {
      short8 vf[4];
#pragma unroll
      for (int j = 0; j < 4; j++)
        vf[j] = *(const short8*)&Vs[(j*16 + lm)*64 + ((kk*4 + q) ^ xlm)*8];
#pragma unroll
      for (int rt = 0; rt < 2; rt++) {
        short8 pf = *(const short8*)&Ps[(wave*32 + rt*16 + lm)*64 + ((kk*4 + q) ^ xlm)*8];
#pragma unroll
        for (int j = 0; j < 4; j++)
          oacc[rt][j] = __builtin_amdgcn_mfma_f32_16x16x32_bf16(pf, vf[j], oacc[rt][j], 0, 0, 0);
      }
    }
    __builtin_amdgcn_s_setprio(0);
  }

  // final l reduction across the 16 lm lanes (q bits untouched by xor<16)
#pragma unroll
  for (int rt = 0; rt < 2; rt++)
#pragma unroll
    for (int r = 0; r < 4; r++) {
      float l = lsum[rt][r];
      l += __shfl_xor(l, 1, 64);
      l += __shfl_xor(l, 2, 64);
      l += __shfl_xor(l, 4, 64);
      l += __shfl_xor(l, 8, 64);
      lsum[rt][r] = 1.0f / l;
    }

#pragma unroll
  for (int rt = 0; rt < 2; rt++)
#pragma unroll
    for (int j = 0; j < 4; j++)
#pragma unroll
      for (int r = 0; r < 4; r++) {
        int row = q0 + wave*32 + rt*16 + q*4 + r;
        if (row < SEQ)
          ctx[((long)(b*SEQ + row))*EMB + h*DKH + j*16 + lm] =
              f2bf(oacc[rt][j][r] * lsum[rt][r]);
      }
}

extern "C" void kernel_launch(void* const* d_in, const int* in_sizes, int n_in,
                              void* d_out, int out_size, void* d_ws, size_t ws_size,
                              hipStream_t stream) {
  const float* x     = (const float*)d_in[0];
  const float* wq    = (const float*)d_in[1];
  const float* bq    = (const float*)d_in[2];
  const float* wk    = (const float*)d_in[3];
  const float* bk    = (const float*)d_in[4];
  const float* wv    = (const float*)d_in[5];
  const float* bv    = (const float*)d_in[6];
  const float* wo    = (const float*)d_in[7];
  const float* bo    = (const float*)d_in[8];
  const float* w1    = (const float*)d_in[9];
  const float* bf1   = (const float*)d_in[10];
  const float* w2    = (const float*)d_in[11];
  const float* bf2   = (const float*)d_in[12];
  const float* ln1g  = (const float*)d_in[13];
  const float* ln1b  = (const float*)d_in[14];
  const float* ln2g  = (const float*)d_in[15];
  const float* ln2b  = (const float*)d_in[16];
  float* out = (float*)d_out;

  char* w = (char*)d_ws;
  size_t off = 0;
  auto alloc = [&](size_t bytes) -> void* {
    void* p = w + off;
    off = (off + bytes + 255) & ~(size_t)255;
    return p;
  };
  unsigned short* WqkvT = (unsigned short*)alloc((size_t)3 * 768 * 768 * 2);
  unsigned short* WoT   = (unsigned short*)alloc((size_t)768 * 768 * 2);
  unsigned short* W1T   = (unsigned short*)alloc((size_t)3072 * 768 * 2);
  unsigned short* W2T   = (unsigned short*)alloc((size_t)768 * 3072 * 2);
  float*          bqkv  = (float*)alloc(2304 * 4);
  unsigned short* hbuf  = (unsigned short*)alloc((size_t)MTOK * EMB * 2);
  unsigned short* qkv   = (unsigned short*)alloc((size_t)MTOK * 3 * EMB * 2);
  unsigned short* vT    = (unsigned short*)alloc((size_t)BHN * DKH * VLD * 2);
  float*          x1    = (float*)alloc((size_t)MTOK * EMB * 4);
  unsigned short* g     = (unsigned short*)alloc((size_t)MTOK * DFF * 2);
  (void)ws_size; (void)in_sizes; (void)n_in; (void)out_size;

  dim3 blk(256);
  const int B128 = ((73 + 7) / 8) * 8;    // 80 padded bands of 128 rows

  transpose_all<<<dim3(96, 24, 6), blk, 0, stream>>>(
      wq, wk, wv, wo, w1, w2, WqkvT, WoT, W1T, W2T);
  concat_bias<<<dim3(9), blk, 0, stream>>>(bq, bk, bv, bqkv);

  ln_kernel<<<dim3(MTOK), blk, 0, stream>>>(x, ln1g, ln1b, hbuf);

  // QKV: [9232,768] @ [768,2304], 128x128 BK=64 (12 iters), CX=18
  gemm_k64<true, false, false, false><<<dim3(18 * B128), blk, 0, stream>>>(
      hbuf, WqkvT, bqkv, nullptr, nullptr, qkv,
      MTOK, 3*EMB, EMB, EMB, EMB, 3*EMB, 18, 73);

  transpose_v<<<dim3(19, 2, BHN), blk, 0, stream>>>(qkv, vT);

  // fused attention v2 (single-buf staging + setprio) -> ctx (hbuf)
  flash_attn2<<<dim3(5, BHN), blk, 0, stream>>>(qkv, vT, hbuf);

  // O-proj + residual -> x1 (fp32); 128x128 BK=64 (12 iters), CX=6
  gemm_k64<true, true, false, true><<<dim3(6 * B128), blk, 0, stream>>>(
      hbuf, WoT, bo, x, x1, nullptr,
      MTOK, EMB, EMB, EMB, EMB, EMB, 6, 73);

  ln_kernel<<<dim3(MTOK), blk, 0, stream>>>(x1, ln2g, ln2b, hbuf);

  // FFN1 + bias + fast GELU -> g (bf16); 128x128 BK=64 (12 iters), CX=24
  gemm_k64<true, false, true, false><<<dim3(24 * B128), blk, 0, stream>>>(
      hbuf, W1T, bf1, nullptr, nullptr, g,
      MTOK, DFF, EMB, EMB, EMB, DFF, 24, 73);

  // FFN2 + bias + residual -> out (fp32); 128x128 BK=64 (48 iters), CX=6
  gemm_k64<true, true, false, true><<<dim3(6 * B128), blk, 0, stream>>>(
      g, W2T, bf2, x1, out, nullptr,
      MTOK, EMB, DFF, DFF, DFF, EMB, 6, 73);
}